// Round 7
// baseline (225.019 us; speedup 1.0000x reference)
//
#include <hip/hip_runtime.h>
#include <hip/hip_bf16.h>

// DotAttention pooled: out[b,d] = sum_t c[b,t]*V[b,t,d],
//   c[b,t] = sum_q exp(s[q,t])/l_q (no-max softmax: s~N(0,1), exp safe),
//   s = (Q K^T)/16,  V == K == inputs.
//
// V8 path (needs 32 MB workspace):
//   conv_k     : inputs fp32 -> bf16, pre-swizzled 32-row tiles (unchanged).
//   attn_fused : per (b, 64-q block), 8 waves = 2 qg (32 q) x 4 tq:
//     QK^T via mfma_f32_32x32x16_bf16, wave-PRIVATE tile ownership:
//       wave (qg,tq) owns tile s*4+tq of each 4-tile slab -> each staged
//       byte is read by only 2 waves (vs 4 qg-waves at 16x16: R6 finding —
//       time scales with LDS read volume, 4 MB/CU = 20 us floor; this
//       halves MFMA count AND halves reads per MFMA -> ~5 us floor).
//     K split in halves (kh): slab = 4 tiles x 32 t x 128 K = 32 KB,
//       double-buffered (2x32 KB); stage-AFTER-barrier (V5 discipline,
//       race-free; V7's stage-before-barrier raced: absmax 0.5 -> 1.0).
//       10 barriers total, vmcnt(0) only after a full compute interval.
//     softmax epilogue (32x32 C/D layout, m74/m101) -> cfin LDS atomics.
//     AV: V rows direct from global (L2-resident kbf slice), unchanged.
// REG DISCIPLINE: (512,4) = 128 cap. a_ 32 VGPR (K-half resident) +
//   acc 64 AGPR + temps ~= 120. (512,6) spilled 76 MB (R4) — never again.
// Fallback path (small ws): previous verified kernels.

typedef __bf16 bf16x8 __attribute__((ext_vector_type(8)));
typedef float  f32x4  __attribute__((ext_vector_type(4)));
typedef float  f32x16 __attribute__((ext_vector_type(16)));
typedef unsigned int u32;

#define B_    128
#define Tn    512
#define Dn    256
#define SCALE 0.0625f  // 1/sqrt(256)

#define WAITV0 asm volatile("s_waitcnt vmcnt(0)" ::: "memory")
#define BARRAW __builtin_amdgcn_s_barrier()
#define SCHED0 __builtin_amdgcn_sched_barrier(0)

// Full-tile LDS/global index (bf16 units) for (row, 16B chunk); xor swizzle.
__device__ __forceinline__ int lidx(int row, int ch) {
  return row * 256 + (((ch ^ (row & 31)) & 31) << 3);
}

__device__ __forceinline__ bf16x8 pack8(float4 v0, float4 v1) {
  bf16x8 w;
  w[0] = (__bf16)v0.x; w[1] = (__bf16)v0.y;
  w[2] = (__bf16)v0.z; w[3] = (__bf16)v0.w;
  w[4] = (__bf16)v1.x; w[5] = (__bf16)v1.y;
  w[6] = (__bf16)v1.z; w[7] = (__bf16)v1.w;
  return w;
}

// Direct global->LDS 16B copy (dest = wave-uniform base + lane*16).
__device__ __forceinline__ void gll16(const __bf16* g, __bf16* l) {
  __builtin_amdgcn_global_load_lds((const u32 __attribute__((address_space(1)))*)g,
                                   (u32 __attribute__((address_space(3)))*)l,
                                   16, 0, 0);
}

// ---------------- pre-pass: K fp32 -> bf16, tile-swizzled ----------------
// kbf[(b*8+tile64)*16384 + c*8] (c = row*32 + p) holds K[b][tile64*64+row]
// logical chunk ch = p ^ (row&31).  32-row tile g is the contiguous 16 KB
// slice at kbf + b*131072 + g*8192 (bf16 units; row&31 tile-local).
__global__ void __launch_bounds__(512) conv_k(const float* __restrict__ inputs,
                                              __bf16* __restrict__ kbf) {
  const int tid = threadIdx.x;
  const int b = blockIdx.x & 127, tile = blockIdx.x >> 7;
#pragma unroll
  for (int i = 0; i < 4; ++i) {
    int c = i * 512 + tid;
    int row = c >> 5, p = c & 31;
    int ch = p ^ (row & 31);
    const float4* s =
        (const float4*)(inputs + ((size_t)b * Tn + tile * 64 + row) * Dn + ch * 8);
    *(bf16x8*)(kbf + (size_t)(b * 8 + tile) * 16384 + (size_t)c * 8) =
        pack8(s[0], s[1]);
  }
}

// ---------------- V8 fused: 32x32 MFMA QK^T + softmax + direct-AV ----------------
__global__ void __launch_bounds__(512, 4) attn_fused(
    const __bf16* __restrict__ kbf, const float* __restrict__ query,
    float* __restrict__ out) {
  // 2 slab buffers x 32 KB (16384 bf16) + scratch (lred 64 f32 | cfin 512
  // f32 = 2304 B). Total 67840 B -> 2 blocks/CU.
  __shared__ __bf16 smem[2 * 16384 + 1152];
  float* lred = (float*)(smem + 2 * 16384);  // [64 q] row-sum accum
  float* cfin = lred + 64;                   // [512 t] col-weight accum

  const int tid = threadIdx.x;
  const int b  = blockIdx.x & 127;  // same-b blocks 128 apart -> same XCD
  const int qt = blockIdx.x >> 7;   // 0..7 (64 q each)

  const int wave = tid >> 6, lane = tid & 63;
  const int l31 = lane & 31, hi = lane >> 5;
  const int qg = wave >> 2;  // 0..1: 32 q rows each
  const int tq = wave & 3;   // owned tile within each slab

  const __bf16* ksrc = kbf + (size_t)b * 131072;  // 8192 bf16 / 32-row tile

  cfin[tid] = 0.f;
  if (tid < 64) lred[tid] = 0.f;  // ordered vs use by QK barriers

  // Stage K-half kh of slab (tiles g4..g4+3) into LDS at bufoff.
  // Lane u = wave*256+i*64+lane -> (tis,row,p); half-swizzle identity:
  // stored chunk for logical ch = kh*16 + (p ^ (row&15)) is
  // p + 16*(kh ^ (row>>4)).  Dest linear: chunk u (16 B per lane).
#define STAGEH(kh, g4, bufoff)                                              \
  {                                                                         \
    _Pragma("unroll") for (int i_ = 0; i_ < 4; ++i_) {                      \
      int u_ = wave * 256 + i_ * 64 + lane;                                 \
      int tis_ = u_ >> 9, c_ = u_ & 511;                                    \
      int row_ = c_ >> 4, p_ = c_ & 15;                                     \
      const __bf16* g_ = ksrc + (size_t)((g4) + tis_) * 8192 + row_ * 256 + \
                         (p_ + (((kh) ^ (row_ >> 4)) << 4)) * 8;            \
      gll16(g_, smem + (bufoff) + u_ * 8);                                  \
    }                                                                       \
  }

  // acc[s]: S[q = qt*64+qg*32+crow(r,hi)][t = (s*4+tq)*32 + l31]
  // crow(r,hi) = (r&3) + 8*(r>>2) + 4*hi   (m74/m101 verified C/D layout)
  f32x16 acc[4];
#pragma unroll
  for (int s = 0; s < 4; ++s)
#pragma unroll
    for (int r = 0; r < 16; ++r) acc[s][r] = 0.f;

  const float* qrow =
      query + ((size_t)b * 512 + qt * 64 + qg * 32 + l31) * Dn;

#pragma unroll
  for (int kh = 0; kh < 2; ++kh) {
    // Prologue of this K-half: stage slab 0, load A-half under its latency.
    STAGEH(kh, 0, 0);

    // A: row = lane&31, k = kh*128 + ks*16 + hi*8 (+0..7) — analog of the
    // verified 16x16 rule (row=lane&15, k=(lane>>4)*8 within K-group).
    bf16x8 a_[8];  // 32 VGPR
#pragma unroll
    for (int ks = 0; ks < 8; ++ks) {
      const float4* p = (const float4*)(qrow + kh * 128 + ks * 16 + hi * 8);
      a_[ks] = pack8(p[0], p[1]);
    }

    WAITV0;  // slab 0 + a_ landed
    BARRAW;
    SCHED0;

#pragma unroll
    for (int s = 0; s < 4; ++s) {
      // Stage next slab into the other buffer (its readers finished last
      // interval, before the barrier we just crossed) — V5 discipline.
      if (s < 3) STAGEH(kh, (s + 1) * 4, ((s + 1) & 1) * 16384);

      // Compute owned tile (tis = tq) of slab s: 8 k-steps.
      const __bf16* cur = smem + (s & 1) * 16384 + tq * 4096 + l31 * 128;
      __builtin_amdgcn_s_setprio(1);
#pragma unroll
      for (int ks = 0; ks < 8; ++ks) {
        bf16x8 bb =
            *(const bf16x8*)(cur + ((((ks * 2 + hi) ^ (l31 & 15)) & 15) << 3));
        acc[s] = __builtin_amdgcn_mfma_f32_32x32x16_bf16(a_[ks], bb, acc[s],
                                                         0, 0, 0);
      }
      __builtin_amdgcn_s_setprio(0);
      WAITV0;  // next slab's loads had the whole compute interval to land
      BARRAW;
      SCHED0;
    }
  }

  // ---- softmax epilogue: exp, row sums, column weights ----
  float rs[16];
#pragma unroll
  for (int r = 0; r < 16; ++r) rs[r] = 0.f;
#pragma unroll
  for (int s = 0; s < 4; ++s)
#pragma unroll
    for (int r = 0; r < 16; ++r) {
      float pv = __expf(acc[s][r] * SCALE);
      acc[s][r] = pv;
      rs[r] += pv;
    }
  // Reduce over the 32 t-cols (lanes within each hi half).
#pragma unroll
  for (int off = 1; off <= 16; off <<= 1)
#pragma unroll
    for (int r = 0; r < 16; ++r) rs[r] += __shfl_xor(rs[r], off);

  if (l31 == 0) {
#pragma unroll
    for (int r = 0; r < 16; ++r)
      atomicAdd(&lred[qg * 32 + (r & 3) + 8 * (r >> 2) + 4 * hi], rs[r]);
  }
  __syncthreads();

  float linv[16];
#pragma unroll
  for (int r = 0; r < 16; ++r)
    linv[r] = 1.f / lred[qg * 32 + (r & 3) + 8 * (r >> 2) + 4 * hi];

#pragma unroll
  for (int s = 0; s < 4; ++s) {
    float v = 0.f;
#pragma unroll
    for (int r = 0; r < 16; ++r) v += acc[s][r] * linv[r];
    atomicAdd(&cfin[(s * 4 + tq) * 32 + l31], v);  // 4 contributors per t
  }
  __syncthreads();

  // ---- AV pass: V rows direct from global (L2-resident kbf slice) ----
  const int dchunk = tid & 31;
  const int tgrp   = tid >> 5;
  float o[8] = {0.f, 0.f, 0.f, 0.f, 0.f, 0.f, 0.f, 0.f};

#pragma unroll 8
  for (int i = 0; i < 32; ++i) {
    int row = tgrp + i * 16;
    int pp = (dchunk ^ (row & 31)) & 31;
    const bf16x8* src = (const bf16x8*)(ksrc + (size_t)(row >> 6) * 16384 +
                                        ((row & 63) * 32 + pp) * 8);
    bf16x8 v = *src;
    float c = cfin[row];  // lanes 0-31 same row -> LDS broadcast
#pragma unroll
    for (int j = 0; j < 8; ++j) o[j] += c * (float)v[j];
  }
  __syncthreads();  // about to overlay smem with ored

  float* ored = (float*)smem;
  f32x4 o0 = {o[0], o[1], o[2], o[3]}, o1 = {o[4], o[5], o[6], o[7]};
  *(f32x4*)&ored[tgrp * 260 + dchunk * 8]     = o0;
  *(f32x4*)&ored[tgrp * 260 + dchunk * 8 + 4] = o1;
  __syncthreads();
  if (tid < 256) {
    float s = 0.f;
#pragma unroll
    for (int g = 0; g < 16; ++g) s += ored[g * 260 + tid];
    atomicAdd(out + (size_t)b * 256 + tid, s);
  }
#undef STAGEH
}

// ---------------- legacy small-ws fallback ----------------
__device__ __forceinline__ void kload(const float* __restrict__ src, int tid,
                                      float4* pre) {
#pragma unroll
  for (int i = 0; i < 4; ++i) {
    int u = i * 512 + tid;
    int row = u >> 5, ch = u & 31;
    const float4* p = (const float4*)(src + row * 256 + ch * 8);
    pre[2 * i]     = p[0];
    pre[2 * i + 1] = p[1];
  }
}

__device__ __forceinline__ void kstore(__bf16* dst, int tid,
                                       const float4* pre) {
#pragma unroll
  for (int i = 0; i < 4; ++i) {
    int u = i * 512 + tid;
    int row = u >> 5, ch = u & 31;
    *(bf16x8*)(dst + lidx(row, ch)) = pack8(pre[2 * i], pre[2 * i + 1]);
  }
}

__global__ void __launch_bounds__(512, 2) attn_qk(
    const float* __restrict__ inputs, const float* __restrict__ query,
    float* __restrict__ c_ws) {
  __shared__ __bf16 smem[128 * 256 + 2 * 64 * 256];
  __bf16* Qs = smem;
  __bf16* Kb[2] = {smem + 128 * 256, smem + 128 * 256 + 64 * 256};

  const int tid  = threadIdx.x;
  const int b  = blockIdx.x & 127;
  const int qt = blockIdx.x >> 7;

  const float* qsrc = query  + ((size_t)b * 512 + (size_t)qt * 128) * Dn;
  const float* ksrc = inputs + (size_t)b * Tn * Dn;

  const int wave = tid >> 6, lane = tid & 63;
  const int quad = lane >> 4, l15 = lane & 15;
  const int qg = wave >> 1;
  const int th = wave & 1;

  float4 pre[2][8];
  kload(ksrc, tid, pre[0]);

#pragma unroll
  for (int i = 0; i < 8; ++i) {
    int u = i * 512 + tid;
    int row = u >> 5, ch = u & 31;
    const float4* p = (const float4*)(qsrc + row * 256 + ch * 8);
    *(bf16x8*)(Qs + lidx(row, ch)) = pack8(p[0], p[1]);
  }

  kload(ksrc + (size_t)1 * 64 * Dn, tid, pre[1]);
  __syncthreads();

  kstore(Kb[0], tid, pre[0]);
  kload(ksrc + (size_t)2 * 64 * Dn, tid, pre[0]);
  __syncthreads();

  f32x4 acc[8][2][2];
  f32x4 zero = {0.f, 0.f, 0.f, 0.f};
#pragma unroll
  for (int tt = 0; tt < 8; ++tt)
#pragma unroll
    for (int ct = 0; ct < 2; ++ct) {
      acc[tt][ct][0] = zero;
      acc[tt][ct][1] = zero;
    }

#pragma unroll
  for (int tt = 0; tt < 8; ++tt) {
    if (tt < 7) kstore(Kb[(tt + 1) & 1], tid, pre[(tt + 1) & 1]);
    if (tt < 5) kload(ksrc + (size_t)(tt + 3) * 64 * Dn, tid, pre[(tt + 1) & 1]);

    const __bf16* cur = Kb[tt & 1];
#pragma unroll
    for (int dc = 0; dc < 8; ++dc) {
      bf16x8 a0 = *(const bf16x8*)(Qs + lidx(qg * 32 + l15, dc * 4 + quad));
      bf16x8 a1 = *(const bf16x8*)(Qs + lidx(qg * 32 + 16 + l15, dc * 4 + quad));
#pragma unroll
      for (int ct = 0; ct < 2; ++ct) {
        bf16x8 bb =
            *(const bf16x8*)(cur + lidx(th * 32 + ct * 16 + l15, dc * 4 + quad));
        acc[tt][ct][0] = __builtin_amdgcn_mfma_f32_16x16x32_bf16(
            a0, bb, acc[tt][ct][0], 0, 0, 0);
        acc[tt][ct][1] = __builtin_amdgcn_mfma_f32_16x16x32_bf16(
            a1, bb, acc[tt][ct][1], 0, 0, 0);
      }
    }
    __syncthreads();
  }

  float* lred  = (float*)Kb[0];
  float* cpart = (float*)Kb[0] + 256;

  float rs[2][4];
#pragma unroll
  for (int m = 0; m < 2; ++m)
#pragma unroll
    for (int r = 0; r < 4; ++r) rs[m][r] = 0.f;
#pragma unroll
  for (int tt = 0; tt < 8; ++tt)
#pragma unroll
    for (int ct = 0; ct < 2; ++ct)
#pragma unroll
      for (int m = 0; m < 2; ++m)
#pragma unroll
        for (int r = 0; r < 4; ++r) {
          float p = __expf(acc[tt][ct][m][r] * SCALE);
          acc[tt][ct][m][r] = p;
          rs[m][r] += p;
        }
#pragma unroll
  for (int off = 1; off <= 8; off <<= 1)
#pragma unroll
    for (int m = 0; m < 2; ++m)
#pragma unroll
      for (int r = 0; r < 4; ++r) rs[m][r] += __shfl_xor(rs[m][r], off);

  if (l15 == 0) {
#pragma unroll
    for (int m = 0; m < 2; ++m)
#pragma unroll
      for (int r = 0; r < 4; ++r)
        lred[(qg * 2 + th) * 32 + m * 16 + quad * 4 + r] = rs[m][r];
  }
  __syncthreads();

  float linv[2][4];
#pragma unroll
  for (int m = 0; m < 2; ++m)
#pragma unroll
    for (int r = 0; r < 4; ++r) {
      int row = m * 16 + quad * 4 + r;
      linv[m][r] =
          1.f / (lred[(qg * 2 + 0) * 32 + row] + lred[(qg * 2 + 1) * 32 + row]);
    }

#pragma unroll
  for (int tt = 0; tt < 8; ++tt)
#pragma unroll
    for (int ct = 0; ct < 2; ++ct) {
      float v = 0.f;
#pragma unroll
      for (int m = 0; m < 2; ++m)
#pragma unroll
        for (int r = 0; r < 4; ++r) v += acc[tt][ct][m][r] * linv[m][r];
      v += __shfl_xor(v, 16);
      v += __shfl_xor(v, 32);
      if (quad == 0)
        cpart[qg * 512 + tt * 64 + th * 32 + ct * 16 + l15] = v;
    }
  __syncthreads();

  float* cout = c_ws + ((size_t)qt * B_ + b) * Tn;
#pragma unroll
  for (int t = tid; t < 512; t += 256) {
    if (t < 512)
      cout[t] = cpart[t] + cpart[512 + t] + cpart[1024 + t] + cpart[1536 + t];
  }
}

template <int NSL>
__global__ void __launch_bounds__(256) attn_av(
    const float* __restrict__ inputs, const float* __restrict__ c_ws,
    float* __restrict__ out) {
  __shared__ float cs[64];
  __shared__ float psum[3][256];
  const int bid = blockIdx.x, tid = threadIdx.x;
  const int b = bid & 127, sl = bid >> 7;

  if (tid < 64) {
    int t = sl * 64 + tid;
    float s = 0.f;
#pragma unroll
    for (int i = 0; i < NSL; ++i) s += c_ws[(size_t)(i * B_ + b) * Tn + t];
    cs[tid] = s;
  }
  __syncthreads();

  const int w = tid >> 6, d4 = tid & 63;
  const float4* vb =
      (const float4*)(inputs + ((size_t)b * Tn + sl * 64 + w * 16) * Dn) + d4;
  float ox = 0.f, oy = 0.f, oz = 0.f, ow = 0.f;
#pragma unroll
  for (int j = 0; j < 16; ++j) {
    float c = cs[w * 16 + j];
    float4 v = vb[(size_t)j * 64];
    ox += c * v.x; oy += c * v.y; oz += c * v.z; ow += c * v.w;
  }
  if (w) {
    float4 t = {ox, oy, oz, ow};
    *(float4*)&psum[w - 1][d4 * 4] = t;
  }
  __syncthreads();
  if (!w) {
    float4 p0 = *(float4*)&psum[0][d4 * 4];
    float4 p1 = *(float4*)&psum[1][d4 * 4];
    float4 p2 = *(float4*)&psum[2][d4 * 4];
    float* op = out + b * 256 + d4 * 4;
    atomicAdd(op + 0, ox + p0.x + p1.x + p2.x);
    atomicAdd(op + 1, oy + p0.y + p1.y + p2.y);
    atomicAdd(op + 2, oz + p0.z + p1.z + p2.z);
    atomicAdd(op + 3, ow + p0.w + p1.w + p2.w);
  }
}

extern "C" void kernel_launch(void* const* d_in, const int* in_sizes, int n_in,
                              void* d_out, int out_size, void* d_ws, size_t ws_size,
                              hipStream_t stream) {
  const float* inputs = (const float*)d_in[0];  // [B,T,D]
  const float* query  = (const float*)d_in[1];  // [B,Q,D]
  float* out  = (float*)d_out;                  // [B,D]

  hipMemsetAsync(out, 0, (size_t)B_ * Dn * sizeof(float), stream);

  const size_t kbytes = (size_t)B_ * Tn * Dn * sizeof(__bf16);  // 32 MB
  if (ws_size >= kbytes) {
    __bf16* kbf = (__bf16*)d_ws;
    conv_k    <<<dim3(1024), dim3(512), 0, stream>>>(inputs, kbf);
    attn_fused<<<dim3(1024), dim3(512), 0, stream>>>(kbf, query, out);
  } else {
    float* c_ws = (float*)d_ws;                 // 1 MB
    attn_qk<<<dim3(512), dim3(512), 0, stream>>>(inputs, query, c_ws);
    attn_av<4><<<dim3(1024), dim3(256), 0, stream>>>(inputs, c_ws, out);
  }
}